// Round 9
// baseline (520.360 us; speedup 1.0000x reference)
//
#include <hip/hip_runtime.h>
#include <hip/hip_bf16.h>

typedef short s16x8 __attribute__((ext_vector_type(8)));
typedef float f32x4 __attribute__((ext_vector_type(4)));

#define LOG2E_2 2.8853900817779268f  // 2*log2(e)

__device__ __forceinline__ float fexp2(float x){ return __builtin_amdgcn_exp2f(x); }
__device__ __forceinline__ float frcp (float x){ return __builtin_amdgcn_rcpf(x); }
__device__ __forceinline__ float ftanh(float v){
    return 1.0f - 2.0f * frcp(1.0f + fexp2(LOG2E_2 * v));
}
__device__ __forceinline__ unsigned short f2bf(float v){
    __hip_bfloat16 h = __float2bfloat16(v);
    return __builtin_bit_cast(unsigned short, h);
}
__device__ __forceinline__ float bf2f(unsigned short u){
    return __bfloat162float(__builtin_bit_cast(__hip_bfloat16, u));
}
__device__ __forceinline__ f32x4 mfma32(s16x8 a, s16x8 b, f32x4 c){
    return __builtin_amdgcn_mfma_f32_16x16x32_bf16(a, b, c, 0, 0, 0);
}
// split fp32x4 -> bf16 hi + residual lo (identical rounding path since round 0)
__device__ __forceinline__ void cvt4(float4 v, ushort4& h, ushort4& l){
    h.x = f2bf(v.x); l.x = f2bf(v.x - bf2f(h.x));
    h.y = f2bf(v.y); l.y = f2bf(v.y - bf2f(h.y));
    h.z = f2bf(v.z); l.z = f2bf(v.z - bf2f(h.z));
    h.w = f2bf(v.w); l.w = f2bf(v.w - bf2f(h.w));
}

// One-shot grid barrier: all NB blocks must be co-resident (guaranteed: 1024 blocks
// = 4/CU x 256 CU; LDS 20.6KB and __launch_bounds__(256,4) -> VGPR<=128 -> 4 blocks/CU).
// Release: agent-scope fetch_add after __threadfence. Acquire: agent-scope load in the
// spin (emits L1/L2 invalidate -> cross-XCD visibility), s_sleep backoff to limit
// invalidate thrash while other blocks compute.
__device__ __forceinline__ void grid_barrier(unsigned* cnt, int t, unsigned target){
    __syncthreads();
    __threadfence();
    if (t == 0) {
        __hip_atomic_fetch_add(cnt, 1u, __ATOMIC_RELEASE, __HIP_MEMORY_SCOPE_AGENT);
        while (__hip_atomic_load(cnt, __ATOMIC_ACQUIRE, __HIP_MEMORY_SCOPE_AGENT) < target) {
            __builtin_amdgcn_s_sleep(32);
        }
    }
    __syncthreads();
}

// ---------- fused: phase1 = k1 (hv) | barrier | phase2 = k2 (P) | barrier |
// ---------- phase3 = k3 (pairwise). Phase internals byte-identical to round 7.
// LDS union: phase1/2 use 4x 5120B bf16 tiles (20480B); phase3 uses 2x 9216B
// float tiles + 1024B wls (19456B). One 20608B byte array, 16B-aligned offsets.
__global__ __launch_bounds__(256, 4) void fused_all(
    const float* __restrict__ l0, const float* __restrict__ l1,
    const float* __restrict__ Wfoh, const float* __restrict__ Wfom,
    const float* __restrict__ cb,
    const float* __restrict__ W2, const float* __restrict__ h2b,
    const float* __restrict__ w, const float* __restrict__ ob,
    unsigned short* __restrict__ hvhi, unsigned short* __restrict__ hvlo,
    float* __restrict__ P, unsigned* __restrict__ bar,
    float* __restrict__ out)
{
    __shared__ __align__(16) unsigned char smem[20608];
    const int t = threadIdx.x;
    const int bid = blockIdx.x;

    // ================= phase 1: hv = tanh(x @ [Wfoh|Wfom] + cb) =================
    {
        unsigned short (*Ah)[32][40] = (unsigned short(*)[32][40])(smem + 0);
        unsigned short (*Al)[32][40] = (unsigned short(*)[32][40])(smem + 5120);
        unsigned short (*Bh)[32][40] = (unsigned short(*)[32][40])(smem + 10240);
        unsigned short (*Bl)[32][40] = (unsigned short(*)[32][40])(smem + 15360);

        const int r0 = (bid >> 5) * 32, c0 = (bid & 31) * 32;
        const int wid = t >> 6, lane = t & 63;
        const int m = lane & 15, quad = lane >> 4;
        const int wm = wid & 1, wn = wid >> 1;

        const int arow = t >> 3, aseg = t & 7;   // A: float4 @ k-cols aseg*4, row arow
        const int nn = t & 31, kq = t >> 5;      // B: col nn, k rows kq*4..kq*4+3

        const float* xr0 = l0 + (r0+arow)*256 + aseg*4;
        const float* xr1 = l1 + (r0+arow)*256 + aseg*4;
        const float* wcol = (c0 < 512) ? (Wfoh + c0 + nn) : (Wfom + (c0 - 512) + nn);

        f32x4 acc = {0,0,0,0};

        float4 fa, fb;
        #define K1_LOAD(k0_) do { \
            const float* pa_ = ((k0_) < 256) ? (xr0 + (k0_)) : (xr1 + ((k0_) - 256)); \
            fa = *(const float4*)pa_; \
            const float* pb_ = wcol + ((k0_) + kq*4) * 512; \
            fb.x = pb_[0]; fb.y = pb_[512]; fb.z = pb_[1024]; fb.w = pb_[1536]; \
        } while(0)
        #define K1_STAGE(buf_) do { \
            ushort4 ah_, al_, bh_, bl_; \
            cvt4(fa, ah_, al_); cvt4(fb, bh_, bl_); \
            *(ushort4*)&Ah[buf_][arow][aseg*4] = ah_; \
            *(ushort4*)&Al[buf_][arow][aseg*4] = al_; \
            *(ushort4*)&Bh[buf_][nn][kq*4] = bh_; \
            *(ushort4*)&Bl[buf_][nn][kq*4] = bl_; \
        } while(0)

        K1_LOAD(0);
        K1_STAGE(0);
        K1_LOAD(32);
        __syncthreads();

        for (int c = 0; c < 16; ++c) {
            const int buf = c & 1;
            {
                const int ko = quad*8;
                s16x8 ah = *(const s16x8*)&Ah[buf][wm*16 + m][ko];
                s16x8 al = *(const s16x8*)&Al[buf][wm*16 + m][ko];
                s16x8 bh = *(const s16x8*)&Bh[buf][wn*16 + m][ko];
                s16x8 bl = *(const s16x8*)&Bl[buf][wn*16 + m][ko];
                acc = mfma32(ah, bh, acc);
                acc = mfma32(ah, bl, acc);
                acc = mfma32(al, bh, acc);
            }
            if (c + 1 < 16) {
                K1_STAGE(buf ^ 1);
                if (c + 2 < 16) K1_LOAD((c + 2) * 32);
                __syncthreads();
            }
        }
        #undef K1_LOAD
        #undef K1_STAGE

        {
            const int col = c0 + wn*16 + m;
            const float bias = cb[col];
            #pragma unroll
            for (int reg = 0; reg < 4; ++reg) {
                const int row = r0 + wm*16 + quad*4 + reg;
                float v = ftanh(acc[reg] + bias);
                unsigned short h = f2bf(v);
                unsigned short l = f2bf(v - bf2f(h));
                hvhi[row*1024 + col] = h;
                hvlo[row*1024 + col] = l;
            }
        }
    }

    grid_barrier(bar + 0, t, 1024u);

    // ================= phase 2: P = exp2(LOG2E_2*(hv_half @ W2_half + bias)) ====
    if (bid < 512) {
        unsigned short (*Ah)[32][40] = (unsigned short(*)[32][40])(smem + 0);
        unsigned short (*Al)[32][40] = (unsigned short(*)[32][40])(smem + 5120);
        unsigned short (*Bh)[32][40] = (unsigned short(*)[32][40])(smem + 10240);
        unsigned short (*Bl)[32][40] = (unsigned short(*)[32][40])(smem + 15360);

        const int r0 = (bid >> 4) * 32, c0 = (bid & 15) * 32;
        const int half = (c0 >= 256) ? 1 : 0;
        const int ho = half * 512;
        const int nw = c0 & 255;
        const int wid = t >> 6, lane = t & 63;
        const int m = lane & 15, quad = lane >> 4;
        const int wm = wid & 1, wn = wid >> 1;

        const int arow = t >> 3, aseg = t & 7;
        const int nn = t & 31, kq = t >> 5;

        const unsigned short* pAh = hvhi + (r0+arow)*1024 + ho + aseg*4;
        const unsigned short* pAl = hvlo + (r0+arow)*1024 + ho + aseg*4;
        const float* wcol = W2 + ho*256 + nw + nn;   // element k: wcol[k*256]

        f32x4 acc = {0,0,0,0};

        uint2 pa_h, pa_l;
        float4 fb;
        #define K2_LOAD(k0_) do { \
            pa_h = *(const uint2*)(pAh + (k0_)); \
            pa_l = *(const uint2*)(pAl + (k0_)); \
            const float* pb_ = wcol + ((k0_) + kq*4) * 256; \
            fb.x = pb_[0]; fb.y = pb_[256]; fb.z = pb_[512]; fb.w = pb_[768]; \
        } while(0)
        #define K2_STAGE(buf_) do { \
            ushort4 bh_, bl_; \
            cvt4(fb, bh_, bl_); \
            *(uint2*)&Ah[buf_][arow][aseg*4] = pa_h; \
            *(uint2*)&Al[buf_][arow][aseg*4] = pa_l; \
            *(ushort4*)&Bh[buf_][nn][kq*4] = bh_; \
            *(ushort4*)&Bl[buf_][nn][kq*4] = bl_; \
        } while(0)

        K2_LOAD(0);
        K2_STAGE(0);
        K2_LOAD(32);
        __syncthreads();

        for (int c = 0; c < 16; ++c) {
            const int buf = c & 1;
            {
                const int ko = quad*8;
                s16x8 ah = *(const s16x8*)&Ah[buf][wm*16 + m][ko];
                s16x8 al = *(const s16x8*)&Al[buf][wm*16 + m][ko];
                s16x8 bh = *(const s16x8*)&Bh[buf][wn*16 + m][ko];
                s16x8 bl = *(const s16x8*)&Bl[buf][wn*16 + m][ko];
                acc = mfma32(ah, bh, acc);
                acc = mfma32(ah, bl, acc);
                acc = mfma32(al, bh, acc);
            }
            if (c + 1 < 16) {
                K2_STAGE(buf ^ 1);
                if (c + 2 < 16) K2_LOAD((c + 2) * 32);
                __syncthreads();
            }
        }
        #undef K2_LOAD
        #undef K2_STAGE

        {
            const int col = c0 + wn*16 + m;
            const float bias = half ? 0.0f : h2b[col];
            #pragma unroll
            for (int reg = 0; reg < 4; ++reg) {
                const int row = r0 + wm*16 + quad*4 + reg;
                P[row*512 + col] = fexp2((acc[reg] + bias) * LOG2E_2);
            }
        }
    }

    grid_barrier(bar + 1, t, 1024u);

    // ================= phase 3: score = ob + sumw - 2*sum_h w[h]/(1+ea*eb) ======
    {
        float (*As)[32][36] = (float(*)[32][36])(smem + 0);
        float (*Bs)[32][36] = (float(*)[32][36])(smem + 9216);
        float* wls          = (float*)(smem + 18432);

        const int tx = t & 15;          // cols tx, tx+16
        const int ty = t >> 4;          // rows ty, ty+16
        const int i0 = (bid >> 5) * 32, j0 = (bid & 31) * 32;

        wls[t] = w[t];

        const int ar = t >> 3, ac = (t & 7) * 4;

        const float* pA = P + (i0 + ar) * 512 + ac;
        const float* pB = P + (j0 + ar) * 512 + 256 + ac;

        float4 ra = *(const float4*)pA;
        float4 rb = *(const float4*)pB;

        *(float4*)&As[0][ar][ac] = ra;
        *(float4*)&Bs[0][ar][ac] = rb;
        ra = *(const float4*)(pA + 32);
        rb = *(const float4*)(pB + 32);
        __syncthreads();

        float acc[2][2] = {};

        #pragma unroll 2
        for (int c = 0; c < 8; ++c) {
            const int buf = c & 1;
            #pragma unroll 4
            for (int hh = 0; hh < 32; hh += 4) {
                float4 wv = *(const float4*)&wls[c*32 + hh];
                float4 av[2], bv[2];
                av[0] = *(const float4*)&As[buf][ty][hh];
                av[1] = *(const float4*)&As[buf][ty+16][hh];
                bv[0] = *(const float4*)&Bs[buf][tx][hh];
                bv[1] = *(const float4*)&Bs[buf][tx+16][hh];
                #pragma unroll
                for (int r = 0; r < 2; ++r)
                    #pragma unroll
                    for (int q = 0; q < 2; ++q) {
                        float u0 = fmaf(av[r].x, bv[q].x, 1.0f);
                        float u1 = fmaf(av[r].y, bv[q].y, 1.0f);
                        float u2 = fmaf(av[r].z, bv[q].z, 1.0f);
                        float u3 = fmaf(av[r].w, bv[q].w, 1.0f);
                        float d01 = u0 * u1;
                        float d23 = u2 * u3;
                        float p01 = fmaf(wv.x, u1, wv.y * u0);
                        float p23 = fmaf(wv.z, u3, wv.w * u2);
                        float num = fmaf(p01, d23, p23 * d01);
                        acc[r][q] = fmaf(num, frcp(d01 * d23), acc[r][q]);
                    }
            }
            if (c + 1 < 8) {
                const int nb = buf ^ 1;
                *(float4*)&As[nb][ar][ac] = ra;
                *(float4*)&Bs[nb][ar][ac] = rb;
                if (c + 2 < 8) {
                    const int off = (c + 2) * 32;
                    ra = *(const float4*)(pA + off);
                    rb = *(const float4*)(pB + off);
                }
                __syncthreads();
            }
        }

        float sumw = 0.0f;
        #pragma unroll
        for (int h = 0; h < 256; h += 4) {
            float4 wv = *(const float4*)&wls[h];
            sumw += (wv.x + wv.y) + (wv.z + wv.w);
        }
        const float base = ob[0] + sumw;
        out[(i0+ty)*1024    + j0+tx]      = base - 2.0f * acc[0][0];
        out[(i0+ty)*1024    + j0+tx+16]   = base - 2.0f * acc[0][1];
        out[(i0+ty+16)*1024 + j0+tx]      = base - 2.0f * acc[1][0];
        out[(i0+ty+16)*1024 + j0+tx+16]   = base - 2.0f * acc[1][1];
    }
}

extern "C" void kernel_launch(void* const* d_in, const int* in_sizes, int n_in,
                              void* d_out, int out_size, void* d_ws, size_t ws_size,
                              hipStream_t stream) {
    const float* l0   = (const float*)d_in[0];  // lstms0 [1024,256]
    const float* l1   = (const float*)d_in[1];  // lstms1 [1024,256]
    const float* Wfoh = (const float*)d_in[2];  // [512,512]
    const float* Wfom = (const float*)d_in[3];  // [512,512]
    const float* cb   = (const float*)d_in[4];  // [1024]
    const float* W2   = (const float*)d_in[5];  // [1024,256]
    const float* h2b  = (const float*)d_in[6];  // [256]
    const float* w    = (const float*)d_in[7];  // [256]
    const float* ob   = (const float*)d_in[8];  // [1]
    float* out = (float*)d_out;                 // [1024,1024]

    // ws layout: hv hi/lo (4MB) + P (2MB) + barrier counters (8B)
    unsigned short* hv_hi = (unsigned short*)d_ws;           // [1024][1024] bf16
    unsigned short* hv_lo = hv_hi + 1024*1024;
    float*          P     = (float*)(hv_lo + 1024*1024);     // [1024][512] fp32
    unsigned*       bar   = (unsigned*)(P + 1024*512);       // 2 one-shot counters

    // ws is re-poisoned each iteration: zero the counters inside the captured graph
    hipMemsetAsync((void*)bar, 0, 2*sizeof(unsigned), stream);

    fused_all<<<1024, 256, 0, stream>>>(l0, l1, Wfoh, Wfom, cb, W2, h2b, w, ob,
                                        hv_hi, hv_lo, P, bar, out);
}

// Round 10
// 117.869 us; speedup vs baseline: 4.4147x; 4.4147x over previous
//
#include <hip/hip_runtime.h>
#include <hip/hip_bf16.h>

typedef short s16x8 __attribute__((ext_vector_type(8)));
typedef float f32x4 __attribute__((ext_vector_type(4)));

#define LOG2E_2 2.8853900817779268f  // 2*log2(e)

__device__ __forceinline__ float fexp2(float x){ return __builtin_amdgcn_exp2f(x); }
__device__ __forceinline__ float frcp (float x){ return __builtin_amdgcn_rcpf(x); }
__device__ __forceinline__ float ftanh(float v){
    return 1.0f - 2.0f * frcp(1.0f + fexp2(LOG2E_2 * v));
}
__device__ __forceinline__ unsigned short f2bf(float v){
    __hip_bfloat16 h = __float2bfloat16(v);
    return __builtin_bit_cast(unsigned short, h);
}
__device__ __forceinline__ float bf2f(unsigned short u){
    return __bfloat162float(__builtin_bit_cast(__hip_bfloat16, u));
}
__device__ __forceinline__ f32x4 mfma32(s16x8 a, s16x8 b, f32x4 c){
    return __builtin_amdgcn_mfma_f32_16x16x32_bf16(a, b, c, 0, 0, 0);
}
// split fp32x4 -> bf16 hi + residual lo (identical rounding path since round 0)
__device__ __forceinline__ void cvt4(float4 v, ushort4& h, ushort4& l){
    h.x = f2bf(v.x); l.x = f2bf(v.x - bf2f(h.x));
    h.y = f2bf(v.y); l.y = f2bf(v.y - bf2f(h.y));
    h.z = f2bf(v.z); l.z = f2bf(v.z - bf2f(h.z));
    h.w = f2bf(v.w); l.w = f2bf(v.w - bf2f(h.w));
}

// ---------- K1': hv = tanh(x @ [Wfoh|Wfom] + cb) -- fp32 in, split done inline ----------
// (R4-verified) Tile 64m x 32n, grid (32,16)=512 blocks, 256 thr. Dbuf LDS, 1 barrier/chunk.
__global__ __launch_bounds__(256) void k1_fused(
    const float* __restrict__ l0, const float* __restrict__ l1,
    const float* __restrict__ Wfoh, const float* __restrict__ Wfom,
    const float* __restrict__ cb,
    unsigned short* __restrict__ hvhi, unsigned short* __restrict__ hvlo)
{
    __shared__ unsigned short Ah[2][64][40], Al[2][64][40], Bh[2][32][40], Bl[2][32][40];
    const int t = threadIdx.x;
    const int r0 = blockIdx.y * 64, c0 = blockIdx.x * 32;
    const int w = t >> 6, lane = t & 63;
    const int m = lane & 15, quad = lane >> 4;

    const int arow = t >> 2, aseg = t & 3;   // A: 8 floats @ cols aseg*8, row arow
    const int nn = t & 31, kq = t >> 5;      // B: col nn, k rows kq*4..kq*4+3

    const float* xrow0 = l0 + (r0+arow)*256 + aseg*8;
    const float* xrow1 = l1 + (r0+arow)*256 + aseg*8;
    const float* wcol  = (c0 < 512) ? (Wfoh + c0 + nn) : (Wfom + (c0 - 512) + nn);

    f32x4 acc0 = {0,0,0,0}, acc1 = {0,0,0,0};

    float4 fa0, fa1, fb;
    #define K1_LOAD(k0_) do { \
        const float* pa_ = ((k0_) < 256) ? (xrow0 + (k0_)) : (xrow1 + ((k0_) - 256)); \
        fa0 = *(const float4*)pa_; \
        fa1 = *(const float4*)(pa_ + 4); \
        const float* pb_ = wcol + ((k0_) + kq*4) * 512; \
        fb.x = pb_[0]; fb.y = pb_[512]; fb.z = pb_[1024]; fb.w = pb_[1536]; \
    } while(0)
    #define K1_STAGE(buf_) do { \
        ushort4 h0_, lo0_, h1_, lo1_, bh_, bl_; \
        cvt4(fa0, h0_, lo0_); cvt4(fa1, h1_, lo1_); cvt4(fb, bh_, bl_); \
        *(ushort4*)&Ah[buf_][arow][aseg*8]     = h0_; \
        *(ushort4*)&Ah[buf_][arow][aseg*8 + 4] = h1_; \
        *(ushort4*)&Al[buf_][arow][aseg*8]     = lo0_; \
        *(ushort4*)&Al[buf_][arow][aseg*8 + 4] = lo1_; \
        *(ushort4*)&Bh[buf_][nn][kq*4] = bh_; \
        *(ushort4*)&Bl[buf_][nn][kq*4] = bl_; \
    } while(0)

    K1_LOAD(0);
    K1_STAGE(0);
    K1_LOAD(32);
    __syncthreads();

    for (int c = 0; c < 16; ++c) {
        const int buf = c & 1;
        {
            const int ko = quad*8;
            s16x8 ah  = *(const s16x8*)&Ah[buf][w*16 + m][ko];
            s16x8 al  = *(const s16x8*)&Al[buf][w*16 + m][ko];
            s16x8 b0h = *(const s16x8*)&Bh[buf][m][ko];
            s16x8 b0l = *(const s16x8*)&Bl[buf][m][ko];
            s16x8 b1h = *(const s16x8*)&Bh[buf][16 + m][ko];
            s16x8 b1l = *(const s16x8*)&Bl[buf][16 + m][ko];
            acc0 = mfma32(ah, b0h, acc0);
            acc0 = mfma32(ah, b0l, acc0);
            acc0 = mfma32(al, b0h, acc0);
            acc1 = mfma32(ah, b1h, acc1);
            acc1 = mfma32(ah, b1l, acc1);
            acc1 = mfma32(al, b1h, acc1);
        }
        if (c + 1 < 16) {
            K1_STAGE(buf ^ 1);
            if (c + 2 < 16) K1_LOAD((c + 2) * 32);
            __syncthreads();
        }
    }
    #undef K1_LOAD
    #undef K1_STAGE

    #pragma unroll
    for (int nt = 0; nt < 2; ++nt) {
        f32x4 a = nt ? acc1 : acc0;
        const int col = c0 + nt*16 + m;
        const float bias = cb[col];
        #pragma unroll
        for (int reg = 0; reg < 4; ++reg) {
            const int row = r0 + w*16 + quad*4 + reg;
            float v = ftanh(a[reg] + bias);
            unsigned short h = f2bf(v);
            unsigned short l = f2bf(v - bf2f(h));
            hvhi[row*1024 + col] = h;
            hvlo[row*1024 + col] = l;
        }
    }
}

// ---------- K2': P[1024][512] = exp2(LOG2E_2*(hv_half @ W2_half + bias)) ----------
// (R4-verified) Tile 32m x 32n, grid (16,32)=512 blocks. Dbuf LDS, inline W2 cvt.
__global__ __launch_bounds__(256) void k2_fused(
    const unsigned short* __restrict__ hvhi, const unsigned short* __restrict__ hvlo,
    const float* __restrict__ W2, const float* __restrict__ h2b,
    float* __restrict__ P)
{
    __shared__ unsigned short Ah[2][32][40], Al[2][32][40], Bh[2][32][40], Bl[2][32][40];
    const int t = threadIdx.x;
    const int r0 = blockIdx.y * 32, c0 = blockIdx.x * 32;
    const int half = (c0 >= 256) ? 1 : 0;
    const int ho = half * 512;
    const int nw = c0 & 255;
    const int w = t >> 6, lane = t & 63;
    const int m = lane & 15, quad = lane >> 4;
    const int wm = w & 1, wn = w >> 1;

    const int arow = t >> 3, aseg = t & 7;   // A: ushort4 @ cols aseg*4, row arow
    const int nn = t & 31, kq = t >> 5;      // B: col nn, k rows kq*4..kq*4+3

    const unsigned short* pAh = hvhi + (r0+arow)*1024 + ho + aseg*4;
    const unsigned short* pAl = hvlo + (r0+arow)*1024 + ho + aseg*4;
    const float* wcol = W2 + ho*256 + nw + nn;   // element k: wcol[k*256]

    f32x4 acc = {0,0,0,0};

    uint2 pa_h, pa_l;
    float4 fb;
    #define K2_LOAD(k0_) do { \
        pa_h = *(const uint2*)(pAh + (k0_)); \
        pa_l = *(const uint2*)(pAl + (k0_)); \
        const float* pb_ = wcol + ((k0_) + kq*4) * 256; \
        fb.x = pb_[0]; fb.y = pb_[256]; fb.z = pb_[512]; fb.w = pb_[768]; \
    } while(0)
    #define K2_STAGE(buf_) do { \
        ushort4 bh_, bl_; \
        cvt4(fb, bh_, bl_); \
        *(uint2*)&Ah[buf_][arow][aseg*4] = pa_h; \
        *(uint2*)&Al[buf_][arow][aseg*4] = pa_l; \
        *(ushort4*)&Bh[buf_][nn][kq*4] = bh_; \
        *(ushort4*)&Bl[buf_][nn][kq*4] = bl_; \
    } while(0)

    K2_LOAD(0);
    K2_STAGE(0);
    K2_LOAD(32);
    __syncthreads();

    for (int c = 0; c < 16; ++c) {
        const int buf = c & 1;
        {
            const int ko = quad*8;
            s16x8 ah = *(const s16x8*)&Ah[buf][wm*16 + m][ko];
            s16x8 al = *(const s16x8*)&Al[buf][wm*16 + m][ko];
            s16x8 bh = *(const s16x8*)&Bh[buf][wn*16 + m][ko];
            s16x8 bl = *(const s16x8*)&Bl[buf][wn*16 + m][ko];
            acc = mfma32(ah, bh, acc);
            acc = mfma32(ah, bl, acc);
            acc = mfma32(al, bh, acc);
        }
        if (c + 1 < 16) {
            K2_STAGE(buf ^ 1);
            if (c + 2 < 16) K2_LOAD((c + 2) * 32);
            __syncthreads();
        }
    }
    #undef K2_LOAD
    #undef K2_STAGE

    {
        const int col = c0 + wn*16 + m;
        const float bias = half ? 0.0f : h2b[col];
        #pragma unroll
        for (int reg = 0; reg < 4; ++reg) {
            const int row = r0 + wm*16 + quad*4 + reg;
            P[row*512 + col] = fexp2((acc[reg] + bias) * LOG2E_2);
        }
    }
}

// ---------- K3 v4: score[i,j] = ob + sumw - 2*sum_h w[h]/(1 + ea[i,h]*eb[j,h]) ----------
// (R4-verified) 32x32 tile, grid (32,32)=1024 blocks (4/CU), dbuf, 2x2 outputs/thread,
// 4-way rcp combine (14 VALU + 1 rcp per 4h), unroll-4 inner (VGPR ~48, no spill).
__global__ __launch_bounds__(256) void k3_pairwise(
    const float* __restrict__ P, const float* __restrict__ w,
    const float* __restrict__ ob, float* __restrict__ out)
{
    __shared__ float As[2][32][68];
    __shared__ float Bs[2][32][68];
    __shared__ float wls[256];
    const int tid = threadIdx.x;
    const int tx = tid & 15;          // cols tx, tx+16
    const int ty = tid >> 4;          // rows ty, ty+16
    const int i0 = blockIdx.y * 32, j0 = blockIdx.x * 32;

    wls[tid] = w[tid];

    const int ar = tid >> 3, ac = (tid & 7) * 8;

    const float* pA = P + (i0 + ar) * 512 + ac;
    const float* pB = P + (j0 + ar) * 512 + 256 + ac;

    float4 ra0 = *(const float4*)(pA);
    float4 ra1 = *(const float4*)(pA + 4);
    float4 rb0 = *(const float4*)(pB);
    float4 rb1 = *(const float4*)(pB + 4);

    *(float4*)&As[0][ar][ac]   = ra0;
    *(float4*)&As[0][ar][ac+4] = ra1;
    *(float4*)&Bs[0][ar][ac]   = rb0;
    *(float4*)&Bs[0][ar][ac+4] = rb1;
    ra0 = *(const float4*)(pA + 64);
    ra1 = *(const float4*)(pA + 68);
    rb0 = *(const float4*)(pB + 64);
    rb1 = *(const float4*)(pB + 68);
    __syncthreads();

    float acc[2][2] = {};

    #pragma unroll 2
    for (int c = 0; c < 4; ++c) {
        const int buf = c & 1;
        #pragma unroll 4
        for (int hh = 0; hh < 64; hh += 4) {
            float4 wv = *(const float4*)&wls[c*64 + hh];
            float4 av[2], bv[2];
            av[0] = *(const float4*)&As[buf][ty][hh];
            av[1] = *(const float4*)&As[buf][ty+16][hh];
            bv[0] = *(const float4*)&Bs[buf][tx][hh];
            bv[1] = *(const float4*)&Bs[buf][tx+16][hh];
            #pragma unroll
            for (int r = 0; r < 2; ++r)
                #pragma unroll
                for (int q = 0; q < 2; ++q) {
                    float u0 = fmaf(av[r].x, bv[q].x, 1.0f);
                    float u1 = fmaf(av[r].y, bv[q].y, 1.0f);
                    float u2 = fmaf(av[r].z, bv[q].z, 1.0f);
                    float u3 = fmaf(av[r].w, bv[q].w, 1.0f);
                    float d01 = u0 * u1;
                    float d23 = u2 * u3;
                    float p01 = fmaf(wv.x, u1, wv.y * u0);
                    float p23 = fmaf(wv.z, u3, wv.w * u2);
                    float num = fmaf(p01, d23, p23 * d01);
                    acc[r][q] = fmaf(num, frcp(d01 * d23), acc[r][q]);
                }
        }
        if (c + 1 < 4) {
            const int nb = buf ^ 1;
            *(float4*)&As[nb][ar][ac]   = ra0;
            *(float4*)&As[nb][ar][ac+4] = ra1;
            *(float4*)&Bs[nb][ar][ac]   = rb0;
            *(float4*)&Bs[nb][ar][ac+4] = rb1;
            if (c + 2 < 4) {
                const int off = (c + 2) * 64;
                ra0 = *(const float4*)(pA + off);
                ra1 = *(const float4*)(pA + off + 4);
                rb0 = *(const float4*)(pB + off);
                rb1 = *(const float4*)(pB + off + 4);
            }
            __syncthreads();
        }
    }

    float sumw = 0.0f;
    #pragma unroll
    for (int h = 0; h < 256; h += 4) {
        float4 wv = *(const float4*)&wls[h];
        sumw += (wv.x + wv.y) + (wv.z + wv.w);
    }
    const float base = ob[0] + sumw;
    out[(i0+ty)*1024    + j0+tx]      = base - 2.0f * acc[0][0];
    out[(i0+ty)*1024    + j0+tx+16]   = base - 2.0f * acc[0][1];
    out[(i0+ty+16)*1024 + j0+tx]      = base - 2.0f * acc[1][0];
    out[(i0+ty+16)*1024 + j0+tx+16]   = base - 2.0f * acc[1][1];
}

extern "C" void kernel_launch(void* const* d_in, const int* in_sizes, int n_in,
                              void* d_out, int out_size, void* d_ws, size_t ws_size,
                              hipStream_t stream) {
    const float* l0   = (const float*)d_in[0];  // lstms0 [1024,256]
    const float* l1   = (const float*)d_in[1];  // lstms1 [1024,256]
    const float* Wfoh = (const float*)d_in[2];  // [512,512]
    const float* Wfom = (const float*)d_in[3];  // [512,512]
    const float* cb   = (const float*)d_in[4];  // [1024]
    const float* W2   = (const float*)d_in[5];  // [1024,256]
    const float* h2b  = (const float*)d_in[6];  // [256]
    const float* w    = (const float*)d_in[7];  // [256]
    const float* ob   = (const float*)d_in[8];  // [1]
    float* out = (float*)d_out;                 // [1024,1024]

    // ws layout: hv hi/lo (4MB) + P (2MB)
    unsigned short* hv_hi = (unsigned short*)d_ws;           // [1024][1024] bf16
    unsigned short* hv_lo = hv_hi + 1024*1024;
    float*          P     = (float*)(hv_lo + 1024*1024);     // [1024][512] fp32

    k1_fused<<<dim3(32,16), 256, 0, stream>>>(l0, l1, Wfoh, Wfom, cb, hv_hi, hv_lo);
    k2_fused<<<dim3(16,32), 256, 0, stream>>>(hv_hi, hv_lo, W2, h2b, P);
    k3_pairwise<<<dim3(32,32), 256, 0, stream>>>(P, w, ob, out);
}